// Round 3
// baseline (574.209 us; speedup 1.0000x reference)
//
#include <hip/hip_runtime.h>
#include <hip/hip_bf16.h>
#include <stdint.h>

#define RCNN_THRES 0.25f
#define YOLO_THRES 0.45f
#define NMS_THRES  0.4f

#define M_BOXES 6144
#define NWORDS  96      // 6144 / 64
#define SORT_N  8192

#define P_ELEMS  750000
#define P_BLOCKS 2930   // ceil(750000/256)
#define R_BLOCKS 1536   // 6144 rows / 4 waves per block
#define B_BLOCKS 24     // 6144 / 256
#define MB_BLOCKS 1536  // mask build: 6144 rows / 4 waves per block

typedef unsigned long long u64;

__device__ inline float wave_sum(float v) {
#pragma unroll
    for (int o = 32; o > 0; o >>= 1) v += __shfl_xor(v, o);
    return v;
}
__device__ inline float wave_max(float v) {
#pragma unroll
    for (int o = 32; o > 0; o >>= 1) v = fmaxf(v, __shfl_xor(v, o));
    return v;
}

__device__ inline float box_loss_term(float c5, float c4) {
    // s = 1/(0.5-0.45) = 20
    float a = fminf(fmaxf((c5 - YOLO_THRES) * 20.0f, 0.0f), 1.0f);
    float b = fminf(fmaxf((c4 - YOLO_THRES) * 20.0f, 0.0f), 1.0f);
    return -a * logf(1.0f - c5 + 0.01f) - b * logf(1.0f - c4 + 0.01f);
}

__device__ inline bool iou_gt(float x1a, float y1a, float x2a, float y2a, float aa,
                              float x1b, float y1b, float x2b, float y2b, float ab) {
    float iw = fmaxf(fminf(x2a, x2b) - fmaxf(x1a, x1b), 0.0f);
    float ih = fmaxf(fminf(y2a, y2b) - fmaxf(y1a, y1b), 0.0f);
    float inter = iw * ih;
    float uni = aa + ab - inter;
    return (inter / fmaxf(uni, 1e-12f)) > NMS_THRES;
}

// ---------------------------------------------------------------------------
// Kernel B: stable descending sort by conf (key = conf_bits<<13 | (8191-idx)),
// then gather sorted corner/area/conf/c5 SoA + valid bit-words.
// Validity (conf > YOLO_THRES) is a PREFIX of the sorted order.
// ---------------------------------------------------------------------------
__global__ __launch_bounds__(1024) void sort_boxes(
    const float* __restrict__ boxes,
    float* __restrict__ sx1, float* __restrict__ sy1,
    float* __restrict__ sx2, float* __restrict__ sy2,
    float* __restrict__ sarea, float* __restrict__ sconf, float* __restrict__ sc5,
    u64* __restrict__ Vw) {
    __shared__ u64 keys[SORT_N];
    const int tid = threadIdx.x;

#pragma unroll
    for (int s = 0; s < SORT_N / 1024; ++s) {
        int p = tid + s * 1024;
        u64 key = 0ull;
        if (p < M_BOXES) {
            unsigned int bits = __float_as_uint(boxes[p * 6 + 4]);
            key = ((u64)bits << 13) | (u64)(8191 - p);
        }
        keys[p] = key;
    }
    for (int k = 2; k <= SORT_N; k <<= 1) {
        for (int j = k >> 1; j > 0; j >>= 1) {
            __syncthreads();
#pragma unroll
            for (int s = 0; s < SORT_N / 2048; ++s) {   // 4096 pairs / 1024 threads
                int q = tid + s * 1024;
                int i = ((q & ~(j - 1)) << 1) | (q & (j - 1));
                int p2 = i | j;
                u64 a = keys[i], b = keys[p2];
                bool up = ((i & k) == 0);
                if ((a < b) == up) { keys[i] = b; keys[p2] = a; }  // descending overall
            }
        }
    }
    __syncthreads();
#pragma unroll
    for (int s = 0; s < SORT_N / 1024; ++s) {
        int p = tid + s * 1024;
        bool validp = false;
        if (p < M_BOXES) {
            int idx = 8191 - (int)(keys[p] & 0x1FFFull);
            const float* b6 = boxes + idx * 6;
            float x = b6[0], y = b6[1], wd = b6[2], ht = b6[3];
            float conf = b6[4], c5 = b6[5];
            sx1[p] = x - wd * 0.5f;
            sx2[p] = x + wd * 0.5f;
            sy1[p] = y - ht * 0.5f;
            sy2[p] = y + ht * 0.5f;
            sarea[p] = wd * ht;
            sconf[p] = conf;
            sc5[p] = c5;
            validp = conf > YOLO_THRES;
        }
        u64 bits = __ballot(validp);
        int word = (tid >> 6) + s * 16;
        if ((tid & 63) == 0 && word < NWORDS) Vw[word] = bits;
    }
}

// ---------------------------------------------------------------------------
// Mega kernel: role-split by blockIdx.
//  [0, MB_BLOCKS)                     : build suppression mask rows (1 wave/row)
//  [MB_BLOCKS, +P_BLOCKS)             : p_loss
//  [.., +R_BLOCKS)                    : r_loss
//  [.., +B_BLOCKS)                    : b_loss + b_cnt
// mask[row][w] bit j = (IoU(row, w*64+j) > thres) && (w*64+j > row)
// ---------------------------------------------------------------------------
__global__ __launch_bounds__(256) void mega_kernel(
    const float* __restrict__ img, const float* __restrict__ p0,
    const float* __restrict__ p1, const float* __restrict__ p2,
    const float* __restrict__ probs, const float* __restrict__ boxes,
    const float* __restrict__ sx1, const float* __restrict__ sy1,
    const float* __restrict__ sx2, const float* __restrict__ sy2,
    const float* __restrict__ sarea, const u64* __restrict__ Vw,
    u64* __restrict__ mask, float* __restrict__ acc) {
    __shared__ float fred[8];
    const int tid = threadIdx.x, lane = tid & 63, wid = tid >> 6;
    const int bid = blockIdx.x;

    if (bid < MB_BLOCKS) {
        int row = bid * 4 + wid;
        if (!((Vw[row >> 6] >> (row & 63)) & 1ull)) return;  // invalid: never kept
        float rx1 = sx1[row], ry1 = sy1[row], rx2 = sx2[row], ry2 = sy2[row];
        float ra = sarea[row];
        u64* mrow = mask + (size_t)row * NWORDS;
        for (int w = row >> 6; w < NWORDS; ++w) {
            if (Vw[w] == 0ull) break;   // prefix property: rest are all-invalid
            int j = w * 64 + lane;
            bool pred = (j > row) &&
                        iou_gt(rx1, ry1, rx2, ry2, ra,
                               sx1[j], sy1[j], sx2[j], sy2[j], sarea[j]);
            u64 bits = __ballot(pred);
            if (lane == 0) mrow[w] = bits;
        }
        return;
    } else if (bid < MB_BLOCKS + P_BLOCKS) {
        int e = (bid - MB_BLOCKS) * 256 + tid;
        float local = 0.0f;
        if (e < P_ELEMS) {
            float v = img[e];
            int c = e / 250000;
            int rem = e - c * 250000;
            int y = rem / 500;
            int x = rem - y * 500;
            if (x >= 50 && x < 450) {
                int px = x - 50;
                if (y >= 75 && y < 125)       v += p0[c * 20000 + (y - 75) * 400 + px];
                else if (y >= 225 && y < 275) v += p1[c * 20000 + (y - 225) * 400 + px];
                else if (y >= 375 && y < 425) v += p2[c * 20000 + (y - 375) * 400 + px];
            }
            local = fmaxf(-v, 0.0f) + fmaxf(v - 1.0f, 0.0f);
        }
        local = wave_sum(local);
        if (lane == 0) fred[wid] = local;
        __syncthreads();
        if (tid == 0) atomicAdd(&acc[0], fred[0] + fred[1] + fred[2] + fred[3]);
    } else if (bid < MB_BLOCKS + P_BLOCKS + R_BLOCKS) {
        int row = (bid - MB_BLOCKS - P_BLOCKS) * 4 + wid;
        const float* pr = probs + row * 81;
        float m = pr[lane];                          // cols 0..63
        if (lane < 16) m = fmaxf(m, pr[64 + lane]);  // cols 64..79 (col 80 excluded)
        m = wave_max(m);
        float t = 0.0f;
        if (lane == 0 && m > RCNN_THRES) {
            float bp = pr[80];
            float cl = fminf(fmaxf((m - RCNN_THRES) * (1.0f / (0.3f - RCNN_THRES)), 0.0f), 1.0f);
            t = -logf(bp + 0.001f) - cl * logf(1.0f - m + 0.001f);
        }
        if (lane == 0) fred[wid] = t;
        __syncthreads();
        if (tid == 0) atomicAdd(&acc[1], fred[0] + fred[1] + fred[2] + fred[3]);
    } else {
        int i = (bid - MB_BLOCKS - P_BLOCKS - R_BLOCKS) * 256 + tid;
        float l = 0.0f, cnt = 0.0f;
        if (i < M_BOXES) {
            float conf = boxes[i * 6 + 4];
            if (conf > YOLO_THRES) {
                float c5 = boxes[i * 6 + 5];
                l = box_loss_term(c5, conf);
                cnt = 1.0f;
            }
        }
        l = wave_sum(l);
        cnt = wave_sum(cnt);
        if (lane == 0) { fred[wid] = l; fred[4 + wid] = cnt; }
        __syncthreads();
        if (tid == 0) {
            atomicAdd(&acc[2], fred[0] + fred[1] + fred[2] + fred[3]);
            atomicAdd(&acc[3], fred[4] + fred[5] + fred[6] + fred[7]);
        }
    }
}

// ---------------------------------------------------------------------------
// Walk kernel: single wave. Per active word w:
//   1. parallel diag-word loads (lane l -> mask[w*64+l][w]) into LDS
//   2. 64-step branch-free register recurrence (no memory dependence)
//   3. kept rows' cross-word suppression loads issued together (coalesced)
// Suppression state in registers: lane l holds sup-word l (sup0), 64+l (sup1).
// ---------------------------------------------------------------------------
__global__ __launch_bounds__(64) void nms_walk(
    const float* __restrict__ acc, const u64* __restrict__ Vw,
    const u64* __restrict__ mask,
    const float* __restrict__ sconf, const float* __restrict__ sc5,
    float* __restrict__ out) {
    __shared__ u64 D[64];
    const int lane = threadIdx.x;
    u64 sup0 = 0ull, sup1 = 0ull;   // suppression words lane, 64+lane
    u64 kw0 = 0ull, kw1 = 0ull;     // keep words lane, 64+lane

    u64 vw0 = Vw[lane];
    u64 vw1 = (lane < NWORDS - 64) ? Vw[64 + lane] : 0ull;

    for (int w = 0; w < NWORDS; ++w) {
        u64 vw = (w < 64) ? __shfl(vw0, w) : __shfl(vw1, w - 64);
        if (vw == 0ull) break;      // prefix property: all later words invalid
        u64 supw = (w < 64) ? __shfl(sup0, w) : __shfl(sup1, w - 64);
        u64 cur = vw & ~supw;       // uniform
        if (cur == 0ull) continue;

        // 1. parallel diagonal-word gather (independent 8B loads, 1/lane)
        u64 dw = 0ull;
        if ((cur >> lane) & 1ull)
            dw = mask[(size_t)(w * 64 + lane) * NWORDS + w];
        D[lane] = dw;               // single wave: no barrier needed

        // 2. branch-free greedy recurrence, zero memory dependence
#pragma unroll
        for (int t = 0; t < 64; ++t) {
            u64 d = D[t];
            cur &= ((cur >> t) & 1ull) ? ~d : ~0ull;
        }
        if (w < 64) { if (lane == w) kw0 = cur; }
        else        { if (lane == w - 64) kw1 = cur; }

        // 3. cross-word suppression: all kept rows' loads issued together
        u64 rem = cur;
        while (rem) {
            int t = __builtin_ctzll(rem);
            rem &= rem - 1;
            const u64* mrow = mask + (size_t)(w * 64 + t) * NWORDS;
            if (lane > w)                          sup0 |= mrow[lane];
            if (64 + lane > w && 64 + lane < NWORDS) sup1 |= mrow[64 + lane];
        }
    }

    // b_nms_loss / b_nms_cnt over kept boxes (keep words broadcast via shfl)
    float nl = 0.0f, nc = 0.0f;
    for (int w = 0; w < NWORDS; ++w) {
        u64 kwv = (w < 64) ? __shfl(kw0, w) : __shfl(kw1, w - 64);
        if ((kwv >> lane) & 1ull) {
            int p = w * 64 + lane;
            nl += box_loss_term(sc5[p], sconf[p]);
            nc += 1.0f;
        }
    }
    nl = wave_sum(nl);
    nc = wave_sum(nc);
    if (lane == 0) {
        float p_loss = acc[0], r_loss = acc[1], b_loss = acc[2], b_cnt = acc[3];
        float yolo = b_loss + nl * (b_cnt / fmaxf(nc, 1.0f));
        out[0] = r_loss * 0.8f + yolo + p_loss;
    }
}

// ---------------------------------------------------------------------------
extern "C" void kernel_launch(void* const* d_in, const int* in_sizes, int n_in,
                              void* d_out, int out_size, void* d_ws, size_t ws_size,
                              hipStream_t stream) {
    const float* img   = (const float*)d_in[0];
    const float* p0    = (const float*)d_in[1];
    const float* p1    = (const float*)d_in[2];
    const float* p2    = (const float*)d_in[3];
    const float* probs = (const float*)d_in[4];
    const float* boxes = (const float*)d_in[5];
    float* out = (float*)d_out;

    char* ws = (char*)d_ws;
    float* acc = (float*)ws;                // 8 floats @ 0
    u64* Vw = (u64*)(ws + 64);              // 96 words
    float* sx1 = (float*)(ws + 1024);
    float* sy1 = sx1 + M_BOXES;
    float* sx2 = sy1 + M_BOXES;
    float* sy2 = sx2 + M_BOXES;
    float* sarea = sy2 + M_BOXES;
    float* sconf = sarea + M_BOXES;
    float* sc5 = sconf + M_BOXES;
    // mask: 6144 rows x 96 words x 8 B = 4.72 MB @ offset 173056 (8-aligned)
    u64* mask = (u64*)(ws + 173056);

    hipMemsetAsync(acc, 0, 64, stream);
    sort_boxes<<<1, 1024, 0, stream>>>(boxes, sx1, sy1, sx2, sy2, sarea, sconf, sc5, Vw);
    mega_kernel<<<MB_BLOCKS + P_BLOCKS + R_BLOCKS + B_BLOCKS, 256, 0, stream>>>(
        img, p0, p1, p2, probs, boxes, sx1, sy1, sx2, sy2, sarea, Vw, mask, acc);
    nms_walk<<<1, 64, 0, stream>>>(acc, Vw, mask, sconf, sc5, out);
}

// Round 6
// 538.402 us; speedup vs baseline: 1.0665x; 1.0665x over previous
//
#include <hip/hip_runtime.h>
#include <hip/hip_bf16.h>
#include <stdint.h>

#define RCNN_THRES 0.25f
#define YOLO_THRES 0.45f
#define NMS_THRES  0.4f

#define M_BOXES 6144
#define NWORDS  96      // 6144 / 64
#define SORT_N  8192

#define P_ELEMS  750000
#define P_BLOCKS 2930   // ceil(750000/256)
#define R_BLOCKS 1536   // 6144 rows / 4 waves per block
#define B_BLOCKS 24     // 6144 / 256
#define MB_BLOCKS 1536  // mask build: 6144 rows / 4 waves per block

typedef unsigned long long u64;

__device__ inline float wave_sum(float v) {
#pragma unroll
    for (int o = 32; o > 0; o >>= 1) v += __shfl_xor(v, o);
    return v;
}
__device__ inline float wave_max(float v) {
#pragma unroll
    for (int o = 32; o > 0; o >>= 1) v = fmaxf(v, __shfl_xor(v, o));
    return v;
}

__device__ inline float box_loss_term(float c5, float c4) {
    // s = 1/(0.5-0.45) = 20
    float a = fminf(fmaxf((c5 - YOLO_THRES) * 20.0f, 0.0f), 1.0f);
    float b = fminf(fmaxf((c4 - YOLO_THRES) * 20.0f, 0.0f), 1.0f);
    return -a * logf(1.0f - c5 + 0.01f) - b * logf(1.0f - c4 + 0.01f);
}

__device__ inline bool iou_gt(float x1a, float y1a, float x2a, float y2a, float aa,
                              float x1b, float y1b, float x2b, float y2b, float ab) {
    float iw = fmaxf(fminf(x2a, x2b) - fmaxf(x1a, x1b), 0.0f);
    float ih = fmaxf(fminf(y2a, y2b) - fmaxf(y1a, y1b), 0.0f);
    float inter = iw * ih;
    float uni = aa + ab - inter;
    return (inter / fmaxf(uni, 1e-12f)) > NMS_THRES;
}

// ---------------------------------------------------------------------------
// Kernel B: stable descending sort by conf (key = conf_bits<<13 | (8191-idx)),
// then gather sorted corner/area/conf/c5 SoA + valid bit-words.
// Validity (conf > YOLO_THRES) is a PREFIX of the sorted order.
// ---------------------------------------------------------------------------
__global__ __launch_bounds__(1024) void sort_boxes(
    const float* __restrict__ boxes,
    float* __restrict__ sx1, float* __restrict__ sy1,
    float* __restrict__ sx2, float* __restrict__ sy2,
    float* __restrict__ sarea, float* __restrict__ sconf, float* __restrict__ sc5,
    u64* __restrict__ Vw) {
    __shared__ u64 keys[SORT_N];
    const int tid = threadIdx.x;

#pragma unroll
    for (int s = 0; s < SORT_N / 1024; ++s) {
        int p = tid + s * 1024;
        u64 key = 0ull;
        if (p < M_BOXES) {
            unsigned int bits = __float_as_uint(boxes[p * 6 + 4]);
            key = ((u64)bits << 13) | (u64)(8191 - p);
        }
        keys[p] = key;
    }
    for (int k = 2; k <= SORT_N; k <<= 1) {
        for (int j = k >> 1; j > 0; j >>= 1) {
            __syncthreads();
#pragma unroll
            for (int s = 0; s < SORT_N / 2048; ++s) {   // 4096 pairs / 1024 threads
                int q = tid + s * 1024;
                int i = ((q & ~(j - 1)) << 1) | (q & (j - 1));
                int p2 = i | j;
                u64 a = keys[i], b = keys[p2];
                bool up = ((i & k) == 0);
                if ((a < b) == up) { keys[i] = b; keys[p2] = a; }  // descending overall
            }
        }
    }
    __syncthreads();
#pragma unroll
    for (int s = 0; s < SORT_N / 1024; ++s) {
        int p = tid + s * 1024;
        bool validp = false;
        if (p < M_BOXES) {
            int idx = 8191 - (int)(keys[p] & 0x1FFFull);
            const float* b6 = boxes + idx * 6;
            float x = b6[0], y = b6[1], wd = b6[2], ht = b6[3];
            float conf = b6[4], c5 = b6[5];
            sx1[p] = x - wd * 0.5f;
            sx2[p] = x + wd * 0.5f;
            sy1[p] = y - ht * 0.5f;
            sy2[p] = y + ht * 0.5f;
            sarea[p] = wd * ht;
            sconf[p] = conf;
            sc5[p] = c5;
            validp = conf > YOLO_THRES;
        }
        u64 bits = __ballot(validp);
        int word = (tid >> 6) + s * 16;
        if ((tid & 63) == 0 && word < NWORDS) Vw[word] = bits;
    }
}

// ---------------------------------------------------------------------------
// Mega kernel: role-split by blockIdx.
//  [0, MB_BLOCKS)                     : build suppression mask rows (1 wave/row)
//  [MB_BLOCKS, +P_BLOCKS)             : p_loss
//  [.., +R_BLOCKS)                    : r_loss
//  [.., +B_BLOCKS)                    : b_loss + b_cnt
// mask[row][w] bit j = (IoU(row, w*64+j) > thres) && (w*64+j > row)
// ---------------------------------------------------------------------------
__global__ __launch_bounds__(256) void mega_kernel(
    const float* __restrict__ img, const float* __restrict__ p0,
    const float* __restrict__ p1, const float* __restrict__ p2,
    const float* __restrict__ probs, const float* __restrict__ boxes,
    const float* __restrict__ sx1, const float* __restrict__ sy1,
    const float* __restrict__ sx2, const float* __restrict__ sy2,
    const float* __restrict__ sarea, const u64* __restrict__ Vw,
    u64* __restrict__ mask, float* __restrict__ acc) {
    __shared__ float fred[8];
    const int tid = threadIdx.x, lane = tid & 63, wid = tid >> 6;
    const int bid = blockIdx.x;

    if (bid < MB_BLOCKS) {
        int row = bid * 4 + wid;
        if (!((Vw[row >> 6] >> (row & 63)) & 1ull)) return;  // invalid: never kept
        float rx1 = sx1[row], ry1 = sy1[row], rx2 = sx2[row], ry2 = sy2[row];
        float ra = sarea[row];
        u64* mrow = mask + (size_t)row * NWORDS;
        for (int w = row >> 6; w < NWORDS; ++w) {
            if (Vw[w] == 0ull) break;   // prefix property: rest are all-invalid
            int j = w * 64 + lane;
            bool pred = (j > row) &&
                        iou_gt(rx1, ry1, rx2, ry2, ra,
                               sx1[j], sy1[j], sx2[j], sy2[j], sarea[j]);
            u64 bits = __ballot(pred);
            if (lane == 0) mrow[w] = bits;
        }
        return;
    } else if (bid < MB_BLOCKS + P_BLOCKS) {
        int e = (bid - MB_BLOCKS) * 256 + tid;
        float local = 0.0f;
        if (e < P_ELEMS) {
            float v = img[e];
            int c = e / 250000;
            int rem = e - c * 250000;
            int y = rem / 500;
            int x = rem - y * 500;
            if (x >= 50 && x < 450) {
                int px = x - 50;
                if (y >= 75 && y < 125)       v += p0[c * 20000 + (y - 75) * 400 + px];
                else if (y >= 225 && y < 275) v += p1[c * 20000 + (y - 225) * 400 + px];
                else if (y >= 375 && y < 425) v += p2[c * 20000 + (y - 375) * 400 + px];
            }
            local = fmaxf(-v, 0.0f) + fmaxf(v - 1.0f, 0.0f);
        }
        local = wave_sum(local);
        if (lane == 0) fred[wid] = local;
        __syncthreads();
        if (tid == 0) atomicAdd(&acc[0], fred[0] + fred[1] + fred[2] + fred[3]);
    } else if (bid < MB_BLOCKS + P_BLOCKS + R_BLOCKS) {
        int row = (bid - MB_BLOCKS - P_BLOCKS) * 4 + wid;
        const float* pr = probs + row * 81;
        float m = pr[lane];                          // cols 0..63
        if (lane < 16) m = fmaxf(m, pr[64 + lane]);  // cols 64..79 (col 80 excluded)
        m = wave_max(m);
        float t = 0.0f;
        if (lane == 0 && m > RCNN_THRES) {
            float bp = pr[80];
            float cl = fminf(fmaxf((m - RCNN_THRES) * (1.0f / (0.3f - RCNN_THRES)), 0.0f), 1.0f);
            t = -logf(bp + 0.001f) - cl * logf(1.0f - m + 0.001f);
        }
        if (lane == 0) fred[wid] = t;
        __syncthreads();
        if (tid == 0) atomicAdd(&acc[1], fred[0] + fred[1] + fred[2] + fred[3]);
    } else {
        int i = (bid - MB_BLOCKS - P_BLOCKS - R_BLOCKS) * 256 + tid;
        float l = 0.0f, cnt = 0.0f;
        if (i < M_BOXES) {
            float conf = boxes[i * 6 + 4];
            if (conf > YOLO_THRES) {
                float c5 = boxes[i * 6 + 5];
                l = box_loss_term(c5, conf);
                cnt = 1.0f;
            }
        }
        l = wave_sum(l);
        cnt = wave_sum(cnt);
        if (lane == 0) { fred[wid] = l; fred[4 + wid] = cnt; }
        __syncthreads();
        if (tid == 0) {
            atomicAdd(&acc[2], fred[0] + fred[1] + fred[2] + fred[3]);
            atomicAdd(&acc[3], fred[4] + fred[5] + fred[6] + fred[7]);
        }
    }
}

// ---------------------------------------------------------------------------
// Walk kernel: single wave, sparse greedy walk.
// Lane l holds: Vw words l / 64+l, sup words l / 64+l, keep words l / 64+l,
// and the DIAGONAL word of row w*64+l for the current word w (prefetched one
// word ahead, unconditional). Every visited bit in the intra-word walk is a
// kept box, so total walk iterations = total kept (~100), each a ctz + shfl
// + 2 ANDs. Cross-word suppression loads (per kept box, one 8B load per lane)
// are deferred until after the walk so their latency lands once per word.
// ---------------------------------------------------------------------------
__global__ __launch_bounds__(64) void nms_walk(
    const float* __restrict__ acc, const u64* __restrict__ Vw,
    const u64* __restrict__ mask,
    const float* __restrict__ sconf, const float* __restrict__ sc5,
    float* __restrict__ out) {
    const int lane = threadIdx.x;
    u64 sup0 = 0ull, sup1 = 0ull;   // suppression words lane, 64+lane
    u64 kw0 = 0ull, kw1 = 0ull;     // keep words lane, 64+lane

    u64 vw0 = Vw[lane];
    u64 vw1 = (lane < NWORDS - 64) ? Vw[64 + lane] : 0ull;
    u64 dw = mask[(size_t)lane * NWORDS];   // diag gather for word 0 (row=lane)

    for (int w = 0; w < NWORDS; ++w) {
        u64 vw = (w < 64) ? __shfl(vw0, w) : __shfl(vw1, w - 64);
        if (vw == 0ull) break;      // prefix property: all later words invalid

        // prefetch next word's diagonal gather (unconditional: garbage rows are
        // never consumed because cur only ever contains valid, unsuppressed bits)
        u64 dwn = 0ull;
        if (w + 1 < NWORDS)
            dwn = mask[(size_t)((w + 1) * 64 + lane) * NWORDS + (w + 1)];

        u64 supw = (w < 64) ? __shfl(sup0, w) : __shfl(sup1, w - 64);
        u64 cur = vw & ~supw;       // uniform across the wave

        // sparse intra-word walk: every visited bit is kept
        u64 rem = cur;
        while (rem) {
            int t = __builtin_ctzll(rem);
            u64 d = __shfl(dw, t);  // diag word of row w*64+t (bits > t only)
            cur &= ~d;
            rem &= ~d;
            rem &= rem - 1;         // clear bit t
        }
        if (w < 64) { if (lane == w) kw0 = cur; }
        else        { if (lane == w - 64) kw1 = cur; }

        // cross-word suppression for all kept bits of this word (loads batched)
        u64 kk = cur;
        while (kk) {
            int t = __builtin_ctzll(kk);
            kk &= kk - 1;
            const u64* mrow = mask + (size_t)(w * 64 + t) * NWORDS;
            if (lane > w)                              sup0 |= mrow[lane];
            if (lane < NWORDS - 64 && 64 + lane > w)   sup1 |= mrow[64 + lane];
        }
        dw = dwn;
    }

    // b_nms_loss / b_nms_cnt: each lane processes its own keep words' set bits
    // (scattered per-lane loads, pipelined; max ~5 bits per word)
    float nl = 0.0f, nc = 0.0f;
    u64 k = kw0;
    while (k) {
        int j = __builtin_ctzll(k);
        k &= k - 1;
        int p = (lane << 6) + j;
        nl += box_loss_term(sc5[p], sconf[p]);
        nc += 1.0f;
    }
    k = kw1;
    while (k) {
        int j = __builtin_ctzll(k);
        k &= k - 1;
        int p = ((64 + lane) << 6) + j;
        nl += box_loss_term(sc5[p], sconf[p]);
        nc += 1.0f;
    }
    nl = wave_sum(nl);
    nc = wave_sum(nc);
    if (lane == 0) {
        float p_loss = acc[0], r_loss = acc[1], b_loss = acc[2], b_cnt = acc[3];
        float yolo = b_loss + nl * (b_cnt / fmaxf(nc, 1.0f));
        out[0] = r_loss * 0.8f + yolo + p_loss;
    }
}

// ---------------------------------------------------------------------------
extern "C" void kernel_launch(void* const* d_in, const int* in_sizes, int n_in,
                              void* d_out, int out_size, void* d_ws, size_t ws_size,
                              hipStream_t stream) {
    const float* img   = (const float*)d_in[0];
    const float* p0    = (const float*)d_in[1];
    const float* p1    = (const float*)d_in[2];
    const float* p2    = (const float*)d_in[3];
    const float* probs = (const float*)d_in[4];
    const float* boxes = (const float*)d_in[5];
    float* out = (float*)d_out;

    char* ws = (char*)d_ws;
    float* acc = (float*)ws;                // 8 floats @ 0
    u64* Vw = (u64*)(ws + 64);              // 96 words
    float* sx1 = (float*)(ws + 1024);
    float* sy1 = sx1 + M_BOXES;
    float* sx2 = sy1 + M_BOXES;
    float* sy2 = sx2 + M_BOXES;
    float* sarea = sy2 + M_BOXES;
    float* sconf = sarea + M_BOXES;
    float* sc5 = sconf + M_BOXES;
    // mask: 6144 rows x 96 words x 8 B = 4.72 MB @ offset 173056 (8-aligned)
    u64* mask = (u64*)(ws + 173056);

    hipMemsetAsync(acc, 0, 64, stream);
    sort_boxes<<<1, 1024, 0, stream>>>(boxes, sx1, sy1, sx2, sy2, sarea, sconf, sc5, Vw);
    mega_kernel<<<MB_BLOCKS + P_BLOCKS + R_BLOCKS + B_BLOCKS, 256, 0, stream>>>(
        img, p0, p1, p2, probs, boxes, sx1, sy1, sx2, sy2, sarea, Vw, mask, acc);
    nms_walk<<<1, 64, 0, stream>>>(acc, Vw, mask, sconf, sc5, out);
}